// Round 20
// baseline (140.963 us; speedup 1.0000x reference)
//
#include <hip/hip_runtime.h>

#define NSEQ 2048
#define DIM  512
#define NKT  64                    // kv tiles of 32
#define TILEB 32768                // 32*512*2 bytes (bf16 tile)
#define SHIFT 12.0f                // static softmax shift (validated R12/R13/R16)
#define SMEMB (4 * TILEB + 4096)   // K0,K1,V0,V1 + 4x1KB per-wave P-lds

typedef __bf16 bf16x8 __attribute__((ext_vector_type(8)));
typedef float  f32x4  __attribute__((ext_vector_type(4)));

__device__ __forceinline__ void gld16(const void* g, void* l) {
  __builtin_amdgcn_global_load_lds(
      (const __attribute__((address_space(1))) unsigned int*)g,
      (__attribute__((address_space(3))) unsigned int*)l, 16, 0, 0);
}

__device__ __forceinline__ unsigned pk2(float lo, float hi) {
  unsigned short a = __builtin_bit_cast(unsigned short, (__bf16)lo);
  unsigned short b = __builtin_bit_cast(unsigned short, (__bf16)hi);
  return (unsigned)a | ((unsigned)b << 16);   // elt0 in bits[15:0]
}

#define MFMA __builtin_amdgcn_mfma_f32_16x16x32_bf16

// ---------- fused pre-pass: blocks 0..511 convert K, 512..1023 convert V.
// K: per-tile [32 kv][512 d] bf16, byte ^= ((row&7)<<4)  (verified layout)
// V: per-tile transposed Vt, byte(d,kv) = (d>>1)*128 + ((((d&1)*64)+kv*2) ^ (((d>>1)&7)<<4))
__global__ __launch_bounds__(256) void prep_kv(const float* __restrict__ ks,
                                               const float* __restrict__ vs,
                                               char* __restrict__ kp,
                                               char* __restrict__ vtp) {
  __shared__ __align__(16) char lds[TILEB];
  int id = blockIdx.x;
  int t = threadIdx.x;
  if (id < 512) {
    int b = id >> 6, kt = id & 63;
    const float* src = ks + ((size_t)(b * NSEQ + kt * 32)) * DIM;
    char* dst = kp + ((size_t)(b * 64 + kt)) * TILEB;
#pragma unroll
    for (int i = 0; i < 8; ++i) {
      int c = t + i * 256;
      int row = c >> 6;
      int d0 = (c & 63) * 8;
      const float4* s4 = (const float4*)(src + row * DIM + d0);
      float4 x = s4[0], y = s4[1];
      bf16x8 h;
      h[0] = (__bf16)x.x; h[1] = (__bf16)x.y; h[2] = (__bf16)x.z; h[3] = (__bf16)x.w;
      h[4] = (__bf16)y.x; h[5] = (__bf16)y.y; h[6] = (__bf16)y.z; h[7] = (__bf16)y.w;
      *(bf16x8*)(dst + row * 1024 + ((d0 * 2) ^ ((row & 7) << 4))) = h;
    }
  } else {
    int v = id - 512;
    int b = v >> 6, kt = v & 63;
    const float* src = vs + ((size_t)(b * NSEQ + kt * 32)) * DIM;
#pragma unroll
    for (int i = 0; i < 8; ++i) {
      int c = t + i * 256;
      int kv = c >> 6;
      int d0 = (c & 63) * 8;
      const float4* s4 = (const float4*)(src + kv * DIM + d0);
      float4 x = s4[0], y = s4[1];
      float vals[8] = {x.x, x.y, x.z, x.w, y.x, y.y, y.z, y.w};
#pragma unroll
      for (int jj = 0; jj < 8; ++jj) {
        int d = d0 + jj;
        int byte = (d >> 1) * 128 + (((((d & 1) * 64) + kv * 2)) ^ (((d >> 1) & 7) << 4));
        *(__bf16*)(lds + byte) = (__bf16)vals[jj];
      }
    }
    __syncthreads();
    char* dst = vtp + ((size_t)(b * 64 + kt)) * TILEB;
#pragma unroll
    for (int i = 0; i < 8; ++i) {
      int c16 = t + i * 256;
      *(bf16x8*)(dst + c16 * 16) = *(const bf16x8*)(lds + c16 * 16);
    }
  }
}

// ---------- main: R16/R19-proven structure; P buffer now LINEAR [16q][32kv]
// (byte = q*64 + kv*2): write = 2x packed b64 per lane (was 8x b16 scatter),
// read = 1x b128 at c*64+16g -> P[q=c][kv=8g..8g+7] (same A-frag as before).
__global__ __launch_bounds__(256) void attn_main(
    const float* __restrict__ qs, const char* __restrict__ kp,
    const char* __restrict__ vtp, const float* __restrict__ scale,
    float* __restrict__ out) {
  extern __shared__ __align__(16) char smem[];
  int b  = blockIdx.x & 7;           // batch -> XCD (L2 locality)
  int qt = blockIdx.x >> 3;
  int tid = threadIdx.x;
  int w = tid >> 6, lane = tid & 63;
  int c = lane & 15, g = lane >> 4;
  int q0 = qt * 64 + w * 16;

  char* kbuf = smem;                 // + (i&1)*TILEB
  char* vbuf = smem + 2 * TILEB;     // + (i&1)*TILEB
  char* plds = smem + 4 * TILEB + w * 1024;

  float cc = 1.4426950408889634f / scale[0];   // log2(e)/scale folded into Q

  // Q fragments (B-operand for swapped QK; lane holds Q[q=c][k*32+g*8..+7])
  bf16x8 qf[16];
#pragma unroll
  for (int k = 0; k < 16; ++k) {
    int d = k * 32 + g * 8;
    const float4* p = (const float4*)(qs + ((size_t)(b * NSEQ + q0 + c)) * DIM + d);
    float4 x = p[0], y = p[1];
    float vals[8] = {x.x, x.y, x.z, x.w, y.x, y.y, y.z, y.w};
    bf16x8 hh;
#pragma unroll
    for (int jj = 0; jj < 8; ++jj) {
      float mlt = (d + jj == 0) ? cc : -cc;    // Minkowski sign fold
      hh[jj] = (__bf16)(vals[jj] * mlt);
    }
    qf[k] = hh;
  }

  f32x4 acc[32];
#pragma unroll
  for (int i = 0; i < 32; ++i) acc[i] = (f32x4){0.f, 0.f, 0.f, 0.f};

  const char* kpb = kp  + (size_t)b * 64 * TILEB;
  const char* vpb = vtp + (size_t)b * 64 * TILEB;

  const int csw = (c & 7) << 4;                // K swizzle term
  const int vt_lane = (c >> 1) * 128 +
      (((((c & 1) * 64) + g * 16)) ^ (((c >> 1) & 7) << 4));  // V B-frag read
  // linear P offsets (q = c per lane): lo chunk kv 4g..4g+3, hi chunk 16+4g..
  const int p_wlo = c * 64 + 8 * g;
  const int p_whi = c * 64 + 32 + 8 * g;
  const int p_rd  = c * 64 + 16 * g;           // P[q=c][kv=8g..8g+7], b128

  // prologue: stage K(0), V(0), K(1)
#pragma unroll
  for (int i = 0; i < 8; ++i) {
    int o = tid * 16 + i * 4096;
    gld16(kpb + o, kbuf + o);
    gld16(vpb + o, vbuf + o);
    gld16(kpb + TILEB + o, kbuf + TILEB + o);
  }
  __syncthreads();

  // ---- QK(0) + P(0) write (static shift, no max); pf read deferred past barrier
  {
    f32x4 sa0 = {0,0,0,0}, sb0 = {0,0,0,0}, sa1 = {0,0,0,0}, sb1 = {0,0,0,0};
    const char* krl = kbuf + c * 1024;
    const char* krh = krl + 16 * 1024;
#pragma unroll
    for (int k = 0; k < 16; ++k) {
      int bir = (k * 64 + g * 16) ^ csw;
      bf16x8 kfl = *(const bf16x8*)(krl + bir);
      bf16x8 kfh = *(const bf16x8*)(krh + bir);
      if (k & 1) { sb0 = MFMA(kfl, qf[k], sb0, 0,0,0); sb1 = MFMA(kfh, qf[k], sb1, 0,0,0); }
      else       { sa0 = MFMA(kfl, qf[k], sa0, 0,0,0); sa1 = MFMA(kfh, qf[k], sa1, 0,0,0); }
    }
    f32x4 sl = sa0 + sb0, sh = sa1 + sb1;
    uint2 lo, hi;
    lo.x = pk2(exp2f(sl[0] - SHIFT), exp2f(sl[1] - SHIFT));
    lo.y = pk2(exp2f(sl[2] - SHIFT), exp2f(sl[3] - SHIFT));
    hi.x = pk2(exp2f(sh[0] - SHIFT), exp2f(sh[1] - SHIFT));
    hi.y = pk2(exp2f(sh[2] - SHIFT), exp2f(sh[3] - SHIFT));
    *(uint2*)(plds + p_wlo) = lo;
    *(uint2*)(plds + p_whi) = hi;
  }
  __syncthreads();   // P(0) drained; kbuf0 free for K(2) staging

  // ---- pipelined main loop: iter t does QK(t+1) || PV(t)
  for (int t = 0; t < NKT - 1; ++t) {
    // hoisted read: P(t) (written before the previous barrier)
    bf16x8 pf = *(const bf16x8*)(plds + p_rd);

    if (t + 2 < NKT) {
      const char* ksrc = kpb + (size_t)(t + 2) * TILEB;
      char* kdst = kbuf + (t & 1) * TILEB;
#pragma unroll
      for (int i = 0; i < 8; ++i) {
        int o = tid * 16 + i * 4096;
        gld16(ksrc + o, kdst + o);
      }
    }
    {
      const char* vsrc = vpb + (size_t)(t + 1) * TILEB;
      char* vdst = vbuf + ((t + 1) & 1) * TILEB;
#pragma unroll
      for (int i = 0; i < 8; ++i) {
        int o = tid * 16 + i * 4096;
        gld16(vsrc + o, vdst + o);
      }
    }

    // ---- merged region: QK(t+1) reads kbuf[(t+1)&1]; PV(t) reads vbuf[t&1]
    f32x4 sa0 = {0,0,0,0}, sb0 = {0,0,0,0}, sa1 = {0,0,0,0}, sb1 = {0,0,0,0};
    const char* krl = kbuf + ((t + 1) & 1) * TILEB + c * 1024;
    const char* krh = krl + 16 * 1024;
    const char* vr  = vbuf + (t & 1) * TILEB + vt_lane;
#pragma unroll
    for (int k = 0; k < 16; ++k) {
      int bir = (k * 64 + g * 16) ^ csw;
      bf16x8 kfl = *(const bf16x8*)(krl + bir);
      bf16x8 kfh = *(const bf16x8*)(krh + bir);
      bf16x8 vf0 = *(const bf16x8*)(vr + (2 * k) * 1024);
      bf16x8 vf1 = *(const bf16x8*)(vr + (2 * k + 1) * 1024);
      if (k & 1) { sb0 = MFMA(kfl, qf[k], sb0, 0,0,0); sb1 = MFMA(kfh, qf[k], sb1, 0,0,0); }
      else       { sa0 = MFMA(kfl, qf[k], sa0, 0,0,0); sa1 = MFMA(kfh, qf[k], sa1, 0,0,0); }
      acc[2 * k]     = MFMA(pf, vf0, acc[2 * k], 0, 0, 0);
      acc[2 * k + 1] = MFMA(pf, vf1, acc[2 * k + 1], 0, 0, 0);
    }
    f32x4 sl = sa0 + sb0, sh = sa1 + sb1;

    // ---- static-shift P(t+1): 2 packed b64 stores (linear layout)
    uint2 lo, hi;
    lo.x = pk2(exp2f(sl[0] - SHIFT), exp2f(sl[1] - SHIFT));
    lo.y = pk2(exp2f(sl[2] - SHIFT), exp2f(sl[3] - SHIFT));
    hi.x = pk2(exp2f(sh[0] - SHIFT), exp2f(sh[1] - SHIFT));
    hi.y = pk2(exp2f(sh[2] - SHIFT), exp2f(sh[3] - SHIFT));
    *(uint2*)(plds + p_wlo) = lo;
    *(uint2*)(plds + p_whi) = hi;

    __syncthreads();   // drain stages + P write; all waves done with buffers
  }

  // ---- tail: PV(NKT-1) with hoisted read of P(NKT-1)
  {
    bf16x8 pf = *(const bf16x8*)(plds + p_rd);
    const char* vr = vbuf + ((NKT - 1) & 1) * TILEB + vt_lane;
#pragma unroll
    for (int dtl = 0; dtl < 32; ++dtl) {
      bf16x8 vf = *(const bf16x8*)(vr + dtl * 1024);
      acc[dtl] = MFMA(pf, vf, acc[dtl], 0, 0, 0);
    }
  }

  // ---- epilogue: Lorentz normalization (softmax denom AND 2^-SHIFT cancel)
#pragma unroll
  for (int r = 0; r < 4; ++r) {
    float ss = 0.f;
#pragma unroll
    for (int dtl = 0; dtl < 32; ++dtl) ss += acc[dtl][r] * acc[dtl][r];
    ss += __shfl_xor(ss, 1);
    ss += __shfl_xor(ss, 2);
    ss += __shfl_xor(ss, 4);
    ss += __shfl_xor(ss, 8);
    float a0 = __shfl(acc[0][r], lane & 48);   // lane c==0 holds O[q][0]
    float d2 = fabsf(2.f * a0 * a0 - ss);
    float inv = rsqrtf(fmaxf(d2, 1e-8f));      // EPS clamp preserved
    float* orow = out + ((size_t)(b * NSEQ + q0 + 4 * g + r)) * DIM + c;
#pragma unroll
    for (int dtl = 0; dtl < 32; ++dtl) orow[dtl * 16] = acc[dtl][r] * inv;
  }
}

extern "C" void kernel_launch(void* const* d_in, const int* in_sizes, int n_in,
                              void* d_out, int out_size, void* d_ws, size_t ws_size,
                              hipStream_t stream) {
  (void)in_sizes; (void)n_in; (void)out_size;
  const float* qs = (const float*)d_in[0];
  const float* ks = (const float*)d_in[1];
  const float* vs = (const float*)d_in[2];
  const float* scale = (const float*)d_in[3];
  // d_in[4] (bias) is uniform across the softmax axis -> softmax-invariant -> unused
  float* out = (float*)d_out;

  size_t need = (size_t)2 * 8 * 64 * TILEB;   // 33.55 MB
  if (ws_size < need) return;
  char* kp  = (char*)d_ws;
  char* vtp = (char*)d_ws + (size_t)8 * 64 * TILEB;

  hipFuncSetAttribute((const void*)attn_main,
                      hipFuncAttributeMaxDynamicSharedMemorySize, SMEMB);

  prep_kv<<<1024, 256, 0, stream>>>(ks, vs, kp, vtp);
  attn_main<<<256, 256, SMEMB, stream>>>(qs, kp, vtp, scale, out);
}